// Round 1
// baseline (98.786 us; speedup 1.0000x reference)
//
#include <hip/hip_runtime.h>

// Ball query: for each query point, collect up to K=64 key indices (in key
// order) with squared distance < R2; pad remaining slots with the first hit
// index (0 if no hits).  B=4, N1=2048, N2=8192.
//
// Strategy: one 64-lane wave per query. Each iteration the wave tests 64
// consecutive keys, ballots the predicate (64-bit mask on CDNA), and uses
// popcount-prefix to write slots in key order. Early exit once K found.

constexpr int   K    = 64;
constexpr float R2   = 0.01f;   // 0.1^2
constexpr int   N1   = 2048;
constexpr int   N2   = 8192;

__global__ __launch_bounds__(256) void ballquery_kernel(
    const float* __restrict__ query,   // [B, N1, 3]
    const float* __restrict__ key,     // [B, N2, 3]
    int* __restrict__ out)             // [B, N1, K]
{
    const int lane = threadIdx.x & 63;
    const int wave_in_block = threadIdx.x >> 6;
    const int q = blockIdx.x * (blockDim.x >> 6) + wave_in_block;  // 0 .. B*N1-1

    const int b = q >> 11;             // q / N1  (N1 = 2048)

    const float* qp = query + q * 3;
    const float qx = qp[0];
    const float qy = qp[1];
    const float qz = qp[2];

    const float* kb = key + (size_t)b * N2 * 3;
    int* op = out + (size_t)q * K;

    int count = 0;       // wave-uniform (updated from ballot)
    int first = 0;       // first hit index; 0 if none (matches argmax of all-false)
    bool have_first = false;

    const unsigned long long lane_mask_lt = (lane == 0) ? 0ull
                                          : (~0ull >> (64 - lane));

    #pragma unroll 4
    for (int c = 0; c < N2 / 64; ++c) {
        if (count >= K) break;
        const int j = (c << 6) + lane;
        const float* kp = kb + j * 3;
        const float dx = kp[0] - qx;
        const float dy = kp[1] - qy;
        const float dz = kp[2] - qz;
        const float d2 = dx * dx + dy * dy + dz * dz;
        const bool within = d2 < R2;

        const unsigned long long mask = __ballot(within);
        if (mask) {
            if (!have_first) {
                first = (c << 6) + __builtin_ctzll(mask);
                have_first = true;
            }
            if (within) {
                const int slot = count + __popcll(mask & lane_mask_lt);
                if (slot < K) op[slot] = j;
            }
            count += __popcll(mask);
        }
    }

    // Pad unfilled slots with `first`.
    const int cnt = count < K ? count : K;
    const int s = cnt + lane;
    if (s < K) op[s] = first;
}

extern "C" void kernel_launch(void* const* d_in, const int* in_sizes, int n_in,
                              void* d_out, int out_size, void* d_ws, size_t ws_size,
                              hipStream_t stream) {
    const float* query = (const float*)d_in[0];   // 4*2048*3 floats
    const float* key   = (const float*)d_in[1];   // 4*8192*3 floats
    int* out = (int*)d_out;                       // 4*2048*64 int32

    const int total_queries = 4 * N1;             // 8192 waves
    const int waves_per_block = 4;                // 256 threads
    const int blocks = total_queries / waves_per_block;  // 2048

    ballquery_kernel<<<blocks, waves_per_block * 64, 0, stream>>>(query, key, out);
}